// Round 2
// baseline (188.587 us; speedup 1.0000x reference)
//
#include <hip/hip_runtime.h>

#pragma clang fp contract(off)

namespace {
constexpr int NB = 2, ND = 100, MH = 28, MW = 28;
constexpr int OH = 512, OW = 512;
constexpr int SH = 128, SW = 128, NC = 32;
constexpr int BMP_ROWS = 172, BMP_PW = 6, BMP_WORDS = BMP_ROWS * BMP_PW; // 1032 words/det

// workspace layout (int32 indices)
constexpr int OFF_COUNTS = 0;                    // NB*32
constexpr int OFF_AREA   = 64;                   // NB*ND
constexpr int OFF_ACC    = OFF_AREA  + NB*ND;
constexpr int OFF_YB     = OFF_ACC   + NB*ND;
constexpr int OFF_XB     = OFF_YB    + NB*ND;
constexpr int OFF_VAL    = OFF_XB    + NB*ND;
constexpr int OFF_FYMIN  = OFF_VAL   + NB*ND;    // float
constexpr int OFF_FXMIN  = OFF_FYMIN + NB*ND;    // float
constexpr int OFF_FHS    = OFF_FXMIN + NB*ND;    // float
constexpr int OFF_FWS    = OFF_FHS   + NB*ND;    // float
constexpr int OFF_SEGCLS = OFF_FWS   + NB*ND;    // bytes region: NB*OH*OW bytes
constexpr int OFF_BMP    = OFF_SEGCLS + (NB*OH*OW)/4; // uint words: NB*ND*BMP_WORDS
}

// ---------------- prep: sort + box bounds + zero counts ----------------
__global__ void k_prep(const float* __restrict__ boxes, const int* __restrict__ classes,
                       const float* __restrict__ scores, int* __restrict__ wsI) {
  const int b = blockIdx.x, t = threadIdx.x;
  float* wsF = (float*)wsI;
  __shared__ float s_sc[ND];
  __shared__ int s_ord[ND];
  if (t < ND) s_sc[t] = scores[b*ND + t];
  if (t < 32) wsI[OFF_COUNTS + b*32 + t] = 0;
  __syncthreads();
  if (t < ND) {
    float sn = s_sc[t];
    int r = 0;
    for (int j = 0; j < ND; ++j) {
      float sj = s_sc[j];
      r += (sj > sn) || (sj == sn && j < t);   // stable descending rank
    }
    s_ord[r] = t;
  }
  __syncthreads();
  if (t < ND) {
    int det = s_ord[t];
    int cls = classes[b*ND + det];
    float sc = s_sc[det];
    const float* bx = boxes + (size_t)(b*ND + det)*4;
    float ymin = bx[0], xmin = bx[1], ymax = bx[2], xmax = bx[3];
    bool keep = (sc > 0.5f) && (cls != 0);
    int ylo = (int)ceilf(ymin), yhi = (int)ceilf(ymax);
    int xlo = (int)ceilf(xmin), xhi = (int)ceilf(xmax);
    ylo = max(ylo, 0); xlo = max(xlo, 0);
    yhi = min(yhi, OH); xhi = min(xhi, OW);
    if (yhi < ylo) yhi = ylo;
    if (xhi < xlo) xhi = xlo;
    if (yhi - ylo > BMP_ROWS)   yhi = ylo + BMP_ROWS;   // safety (shouldn't trigger)
    if (xhi - xlo > BMP_PW*32)  xhi = xlo + BMP_PW*32;
    if (!keep) { yhi = ylo; xhi = xlo; }                // empty box -> empty mask
    float hs  = (ymax > ymin) ? (28.0f / (ymax - ymin)) : 0.0f;
    float wsc = (xmax > xmin) ? (28.0f / (xmax - xmin)) : 0.0f;
    int g = b*ND + t;
    wsI[OFF_YB  + g] = ylo | (yhi << 16);
    wsI[OFF_XB  + g] = xlo | (xhi << 16);
    wsI[OFF_VAL + g] = (det + 1) | (cls << 16);
    wsF[OFF_FYMIN + g] = ymin;
    wsF[OFF_FXMIN + g] = xmin;
    wsF[OFF_FHS   + g] = hs;
    wsF[OFF_FWS   + g] = wsc;
  }
}

// ---------------- seg: bilinear 128->512 resize + argmax + class counts ----------------
__global__ void k_seg(const float* __restrict__ seg, int* __restrict__ wsI) {
  const int t = threadIdx.x;
  const int pid = blockIdx.x*256 + t;            // 0 .. NB*OH*OW-1
  const int b = pid >> 18;
  const int p = pid & (OH*OW - 1);
  const int y = p >> 9, x = p & (OW - 1);
  __shared__ unsigned int hist[NC];
  if (t < NC) hist[t] = 0u;
  __syncthreads();

  float syf = ((float)y + 0.5f) * 0.25f - 0.5f;  // exact (eighths)
  float y0f = floorf(syf);
  float fy = syf - y0f;
  int y0 = (int)y0f, y1 = y0 + 1;
  if (y0 < 0)            { y0 = 0; y1 = 0; fy = 0.0f; }  // single tap, weight exactly 1
  else if (y1 > SH - 1)  { y1 = SH - 1; fy = 0.0f; }
  float sxf = ((float)x + 0.5f) * 0.25f - 0.5f;
  float x0f = floorf(sxf);
  float fx = sxf - x0f;
  int x0 = (int)x0f, x1 = x0 + 1;
  if (x0 < 0)            { x0 = 0; x1 = 0; fx = 0.0f; }
  else if (x1 > SW - 1)  { x1 = SW - 1; fx = 0.0f; }
  float wy = 1.0f - fy, wx = 1.0f - fx;

  const float4* p00 = (const float4*)(seg + ((size_t)(b*SH + y0)*SW + x0)*NC);
  const float4* p01 = (const float4*)(seg + ((size_t)(b*SH + y0)*SW + x1)*NC);
  const float4* p10 = (const float4*)(seg + ((size_t)(b*SH + y1)*SW + x0)*NC);
  const float4* p11 = (const float4*)(seg + ((size_t)(b*SH + y1)*SW + x1)*NC);
  float best = -3.4e38f;
  int bi = 0;
  #pragma unroll
  for (int cc = 0; cc < NC/4; ++cc) {
    float4 a = p00[cc], bb = p01[cc], c2 = p10[cc], d = p11[cc];
    float av[4] = {a.x, a.y, a.z, a.w};
    float bv[4] = {bb.x, bb.y, bb.z, bb.w};
    float cv[4] = {c2.x, c2.y, c2.z, c2.w};
    float dv[4] = {d.x, d.y, d.z, d.w};
    #pragma unroll
    for (int j = 0; j < 4; ++j) {
      float t0 = wy*av[j] + fy*cv[j];   // height pass first (matches XLA dim order)
      float t1 = wy*bv[j] + fy*dv[j];
      float v  = wx*t0 + fx*t1;
      int ch = cc*4 + j;
      if (v > best) { best = v; bi = ch; }  // strict > keeps first max (jnp.argmax)
    }
  }
  ((unsigned char*)wsI)[OFF_SEGCLS*4 + pid] = (unsigned char)bi;
  if (bi >= 2) atomicAdd(&hist[bi], 1u);
  __syncthreads();
  if (t < NC) {
    unsigned int h = hist[t];
    if (h) atomicAdd((unsigned int*)&wsI[OFF_COUNTS + b*32 + t], h);
  }
}

// ---------------- mask: per-det binary bitmap + area ----------------
__global__ void k_mask(const float* __restrict__ dmasks, int* __restrict__ wsI) {
  const int g = blockIdx.x;       // b*ND + sorted k
  const int t = threadIdx.x;      // 256
  const float* wsF = (const float*)wsI;
  __shared__ float sm[MH*MW];
  __shared__ int s_area;
  const int yb = wsI[OFF_YB + g], xb = wsI[OFF_XB + g];
  const int ylo = yb & 0xffff, yhi = yb >> 16;
  const int xlo = xb & 0xffff, xhi = xb >> 16;
  const int rows = yhi - ylo, width = xhi - xlo;
  unsigned int* bmp = (unsigned int*)wsI + OFF_BMP + g*BMP_WORDS;
  for (int i = t; i < BMP_WORDS; i += 256) bmp[i] = 0u;
  if (t == 0) s_area = 0;
  if (rows <= 0 || width <= 0) {     // uniform branch
    if (t == 0) wsI[OFF_AREA + g] = 0;
    return;
  }
  const int det = (wsI[OFF_VAL + g] & 0xffff) - 1;
  const int b = g / ND;
  const float* mp = dmasks + (size_t)(b*ND + det)*(MH*MW);
  for (int i = t; i < MH*MW; i += 256) sm[i] = mp[i];
  const float ymin = wsF[OFF_FYMIN + g], xmin = wsF[OFF_FXMIN + g];
  const float hs = wsF[OFF_FHS + g], wsc = wsF[OFF_FWS + g];
  __syncthreads();
  const int words_x = (width + 31) >> 5;
  const int totalw = rows * words_x;
  const int bit = t & 31;
  for (int wi = (t >> 5); wi < totalw; wi += 8) {
    int r = wi / words_x;
    int w = wi - r*words_x;
    int y = ylo + r;
    int x = xlo + (w << 5) + bit;
    bool pred = false;
    if (x < xhi) {
      // exact op order of _paste_one (fp contract off)
      float ty = ((float)y + 0.5f); ty = ty - ymin; ty = ty * hs;  float my = ty - 0.5f;
      float tx = ((float)x + 0.5f); tx = tx - xmin; tx = tx * wsc; float mx = tx - 0.5f;
      float y0f = floorf(my), x0f = floorf(mx);
      float ly = my - y0f, lx = mx - x0f;
      int y0 = (int)y0f, x0 = (int)x0f;
      int y1 = min(max(y0 + 1, 0), MH - 1);
      int x1 = min(max(x0 + 1, 0), MW - 1);
      y0 = min(max(y0, 0), MH - 1);
      x0 = min(max(x0, 0), MW - 1);
      float v00 = sm[y0*MW + x0], v01 = sm[y0*MW + x1];
      float v10 = sm[y1*MW + x0], v11 = sm[y1*MW + x1];
      float omlx = 1.0f - lx, omly = 1.0f - ly;
      float top = omlx*v00 + lx*v01;
      float bot = omlx*v10 + lx*v11;
      float outv = omly*top + ly*bot;
      pred = outv > 0.5f;
    }
    unsigned long long m = __ballot(pred);
    unsigned int word = (t & 32) ? (unsigned int)(m >> 32) : (unsigned int)m;
    if (bit == 0) {
      bmp[r*BMP_PW + w] = word;              // FIXED: row stride = BMP_PW (was words_x)
      if (word) atomicAdd(&s_area, __popc(word));
    }
  }
  __syncthreads();
  if (t == 0) wsI[OFF_AREA + g] = s_area;
}

// ---------------- scan: sequential overlap/accept over sorted dets ----------------
__global__ void __launch_bounds__(1024) k_scan(int* __restrict__ wsI) {
  const int b = blockIdx.x, t = threadIdx.x;
  __shared__ unsigned int occ[OH*OW/32];   // 8192 words = 32KB, full canvas occupancy
  __shared__ int s_ovl;
  __shared__ int s_acc;
  for (int i = t; i < OH*OW/32; i += 1024) occ[i] = 0u;
  __syncthreads();
  for (int k = 0; k < ND; ++k) {
    const int g = b*ND + k;
    const int area = wsI[OFF_AREA + g];
    if (area <= 0) {                       // uniform: empty mask -> no effect
      if (t == 0) wsI[OFF_ACC + g] = 0;
      continue;
    }
    const int yb = wsI[OFF_YB + g], xb = wsI[OFF_XB + g];
    const int ylo = yb & 0xffff, xlo = xb & 0xffff;
    const int rows = (yb >> 16) - ylo;
    const int width = (xb >> 16) - xlo;
    const int words_x = (width + 31) >> 5;
    const int totalw = rows * words_x;
    const unsigned int* bmp = (const unsigned int*)wsI + OFF_BMP + g*BMP_WORDS;
    if (t == 0) s_ovl = 0;
    __syncthreads();
    int cnt = 0;
    for (int wi = t; wi < totalw; wi += 1024) {
      int r = wi / words_x, w = wi - r*words_x;
      unsigned int bm = bmp[r*BMP_PW + w];
      if (bm) {
        int gx0 = xlo + (w << 5);
        int q = gx0 >> 5, sh = gx0 & 31;
        int rb = (ylo + r) << 4;
        unsigned int o = occ[rb + q] >> sh;
        if (sh && q < 15) o |= occ[rb + q + 1] << (32 - sh);
        cnt += __popc(bm & o);
      }
    }
    #pragma unroll
    for (int off = 32; off > 0; off >>= 1) cnt += __shfl_xor(cnt, off);
    if ((t & 63) == 0 && cnt) atomicAdd(&s_ovl, cnt);
    __syncthreads();
    if (t == 0) {
      float frac = (float)s_ovl / (float)area;   // area>=1 -> max(area,1)==area
      int a = (frac < 0.5f) ? 1 : 0;
      s_acc = a;
      wsI[OFF_ACC + g] = a;
    }
    __syncthreads();
    if (s_acc) {
      for (int wi = t; wi < totalw; wi += 1024) {
        int r = wi / words_x, w = wi - r*words_x;
        unsigned int bm = bmp[r*BMP_PW + w];
        if (bm) {
          int gx0 = xlo + (w << 5);
          int q = gx0 >> 5, sh = gx0 & 31;
          int rb = (ylo + r) << 4;
          atomicOr(&occ[rb + q], bm << sh);
          if (sh && q < 15) atomicOr(&occ[rb + q + 1], bm >> (32 - sh));
        }
      }
    }
    __syncthreads();
  }
}

// ---------------- final: paint first accepted det per pixel + stuff merge ----------------
__global__ void k_final(const int* __restrict__ wsI, int* __restrict__ out) {
  const int t = threadIdx.x;
  const int pid = blockIdx.x*256 + t;
  const int b = pid >> 18;
  const int y = (pid >> 9) & (OH - 1);
  const int x = pid & (OW - 1);
  __shared__ unsigned int s_yb[ND], s_xb[ND], s_val[ND];
  __shared__ int s_cnt[NC];
  if (t < ND) {
    int g = b*ND + t;
    int acc = wsI[OFF_ACC + g];
    s_yb[t] = acc ? (unsigned int)wsI[OFF_YB + g] : 0u;   // 0 => empty range
    s_xb[t] = (unsigned int)wsI[OFF_XB + g];
    s_val[t] = (unsigned int)wsI[OFF_VAL + g];
  }
  if (t >= 128 && t < 128 + NC) s_cnt[t - 128] = wsI[OFF_COUNTS + b*32 + (t - 128)];
  __syncthreads();
  int inst = -1, cat = 0;
  const unsigned int yu = (unsigned int)y, xu = (unsigned int)x;
  const unsigned int* bmpAll = (const unsigned int*)wsI + OFF_BMP + b*ND*BMP_WORDS;
  for (int k = 0; k < ND; ++k) {
    unsigned int yb = s_yb[k];
    if (yu >= (yb & 0xffffu) && yu < (yb >> 16)) {
      unsigned int xb = s_xb[k];
      if (xu >= (xb & 0xffffu) && xu < (xb >> 16)) {
        int ylo = (int)(yb & 0xffffu), xlo = (int)(xb & 0xffffu);
        int cb = x - xlo;
        unsigned int word = bmpAll[k*BMP_WORDS + (y - ylo)*BMP_PW + (cb >> 5)];
        if ((word >> (cb & 31)) & 1u) {
          unsigned int val = s_val[k];
          inst = (int)(val & 0xffffu);
          cat  = (int)(val >> 16);
          break;
        }
      }
    }
  }
  int cls = ((const unsigned char*)wsI)[OFF_SEGCLS*4 + pid];
  int catf = cat;
  if (cat == 0 && cls >= 2 && s_cnt[cls] > 4096) catf = cls + 90;
  out[pid] = inst;
  out[NB*OH*OW + pid] = catf;
}

extern "C" void kernel_launch(void* const* d_in, const int* in_sizes, int n_in,
                              void* d_out, int out_size, void* d_ws, size_t ws_size,
                              hipStream_t stream) {
  const float* boxes   = (const float*)d_in[0];
  const int*   classes = (const int*)d_in[1];
  const float* scores  = (const float*)d_in[2];
  const float* dmasks  = (const float*)d_in[3];
  const float* seg     = (const float*)d_in[4];
  int* wsI = (int*)d_ws;
  int* out = (int*)d_out;

  k_prep<<<NB, 128, 0, stream>>>(boxes, classes, scores, wsI);
  k_seg <<<(NB*OH*OW)/256, 256, 0, stream>>>(seg, wsI);
  k_mask<<<NB*ND, 256, 0, stream>>>(dmasks, wsI);
  k_scan<<<NB, 1024, 0, stream>>>(wsI);
  k_final<<<(NB*OH*OW)/256, 256, 0, stream>>>(wsI, out);
}